// Round 1
// baseline (173.044 us; speedup 1.0000x reference)
//
#include <hip/hip_runtime.h>
#include <hip/hip_bf16.h>
#include <math.h>

// B=4, T=128, S=512, D=512. Outputs: attn_h (4,128,512) then align (4,128,512), fp32.
// 3-kernel pipeline (R6: softmax kernel eliminated via exp-in-K2 + normalize-in-K4):
//   K1 fused_front (641): Ew=exp(2(inp@Wq^T+bq)), Eu=exp(2 ctx@Wc^T),
//      GT[b]=(WL@ctx_b^T) bf16, Y0=inp@WR^T+bout, block 640 zeroes rowsum.
//   K2 align_exp (2048): E[b,t,s] = exp(V - 2*sum_d v[d]/(1+Ew*Eu))  (== exp(sum v*tanh))
//      + atomicAdd per-row sums (no max-pass: |S| bounded, exp safe in fp32).
//   K3 gemm_att_sm (64): attn = (E*rinv)_bf16 @ GT^T + Y0 (MFMA, K=512);
//      y==0 blocks also write alignv = E*rinv (fp32).

typedef __attribute__((ext_vector_type(8))) short short8;
typedef __attribute__((ext_vector_type(4))) float f32x4;
typedef unsigned short ushort_t;

static __device__ __forceinline__ unsigned short f2bf(float x) {
    union { __hip_bfloat16 h; unsigned short u; } c;
    c.h = __float2bfloat16(x);
    return c.u;
}
static __device__ __forceinline__ int bf2x(float lo, float hi) {
    return (int)(((unsigned)f2bf(hi) << 16) | (unsigned)f2bf(lo));
}

template<bool BF>
static __device__ __forceinline__ void load16(const void* base, size_t elemoff,
                                              int4& r0, int4& r1) {
    if (BF) {
        const int4* p = (const int4*)((const ushort_t*)base + elemoff);
        r0 = p[0]; r1 = p[1];
    } else {
        const float4* p = (const float4*)((const float*)base + elemoff);
        float4 a = p[0], b = p[1], c = p[2], d = p[3];
        r0.x = bf2x(a.x, a.y); r0.y = bf2x(a.z, a.w);
        r0.z = bf2x(b.x, b.y); r0.w = bf2x(b.z, b.w);
        r1.x = bf2x(c.x, c.y); r1.y = bf2x(c.z, c.w);
        r1.z = bf2x(d.x, d.y); r1.w = bf2x(d.z, d.w);
    }
}

// fp32 load + per-row scale + bf16 pack (for P = E * rinv staging)
static __device__ __forceinline__ void load16s(const void* base, size_t elemoff,
                                               float s, int4& r0, int4& r1) {
    const float4* p = (const float4*)((const float*)base + elemoff);
    float4 a = p[0], b = p[1], c = p[2], d = p[3];
    a.x *= s; a.y *= s; a.z *= s; a.w *= s;
    b.x *= s; b.y *= s; b.z *= s; b.w *= s;
    c.x *= s; c.y *= s; c.z *= s; c.w *= s;
    d.x *= s; d.y *= s; d.z *= s; d.w *= s;
    r0.x = bf2x(a.x, a.y); r0.y = bf2x(a.z, a.w);
    r0.z = bf2x(b.x, b.y); r0.w = bf2x(b.z, b.w);
    r1.x = bf2x(c.x, c.y); r1.y = bf2x(c.z, c.w);
    r1.z = bf2x(d.x, d.y); r1.w = bf2x(d.z, d.w);
}

// ---------------------------------------------------------------------------
// MFMA NT GEMM tile: C[m,n] = sum_k A[m,k]*W[n,k] (+bias). 64x64 tile, BK=64,
// 256 thr = 4 waves (2x2 of 32x32), 2x2 MFMA 16x16x32 per 32-K step.
// LDS rows padded to 72 bf16 (<=2-way bank aliasing on b128 = free).
// EPI: 0 fp32+bias; 1 fp32 exp(2*(x+bias)); 2 bf16; 3 fp32 + partial[].
// A_SCALE: A is fp32 scaled per-row by ascale[srow] (LDS) before bf16 pack.
// ---------------------------------------------------------------------------
template<bool A_BF, bool W_BF, int EPI, bool A_SCALE = false>
static __device__ __forceinline__ void gemm_body(
    ushort_t* As, ushort_t* Ws,
    const void* A, const void* W, const float* bias, const float* partial,
    void* Cv, int K, int lda, int ldw, int ldc, int bm, int bn,
    const float* ascale = nullptr)
{
    const int tid = threadIdx.x;
    const int wave = tid >> 6, lane = tid & 63;
    const int mh = (wave & 1) * 32, nh = (wave >> 1) * 32;
    const int quad = lane >> 4, l16 = lane & 15;
    const int srow = tid >> 2, schunk = tid & 3;

    const size_t aoff = (size_t)(bm + srow) * lda + schunk * 16;
    const size_t woff = (size_t)(bn + srow) * ldw + schunk * 16;
    int4* AsW = (int4*)&As[srow * 72 + schunk * 16];
    int4* WsW = (int4*)&Ws[srow * 72 + schunk * 16];

    const float asc = A_SCALE ? ascale[srow] : 1.f;

    f32x4 acc00 = {0.f, 0.f, 0.f, 0.f}, acc01 = acc00, acc10 = acc00, acc11 = acc00;

    int4 a0r, a1r, w0r, w1r;
    if (A_SCALE) load16s(A, aoff, asc, a0r, a1r);
    else         load16<A_BF>(A, aoff, a0r, a1r);
    load16<W_BF>(W, woff, w0r, w1r);

    for (int k0 = 0; k0 < K; k0 += 64) {
        AsW[0] = a0r; AsW[1] = a1r;
        WsW[0] = w0r; WsW[1] = w1r;
        __syncthreads();
        if (k0 + 64 < K) {
            if (A_SCALE) load16s(A, aoff + k0 + 64, asc, a0r, a1r);
            else         load16<A_BF>(A, aoff + k0 + 64, a0r, a1r);
            load16<W_BF>(W, woff + k0 + 64, w0r, w1r);
        }
        #pragma unroll
        for (int kk = 0; kk < 64; kk += 32) {
            short8 a0 = *(const short8*)&As[(mh + l16) * 72 + kk + quad * 8];
            short8 a1 = *(const short8*)&As[(mh + 16 + l16) * 72 + kk + quad * 8];
            short8 b0 = *(const short8*)&Ws[(nh + l16) * 72 + kk + quad * 8];
            short8 b1 = *(const short8*)&Ws[(nh + 16 + l16) * 72 + kk + quad * 8];
            acc00 = __builtin_amdgcn_mfma_f32_16x16x32_bf16(a0, b0, acc00, 0, 0, 0);
            acc01 = __builtin_amdgcn_mfma_f32_16x16x32_bf16(a0, b1, acc01, 0, 0, 0);
            acc10 = __builtin_amdgcn_mfma_f32_16x16x32_bf16(a1, b0, acc10, 0, 0, 0);
            acc11 = __builtin_amdgcn_mfma_f32_16x16x32_bf16(a1, b1, acc11, 0, 0, 0);
        }
        __syncthreads();
    }

    const int col0 = bn + nh + l16;
    const int col1 = col0 + 16;
    float bias0 = bias ? bias[col0] : 0.f;
    float bias1 = bias ? bias[col1] : 0.f;

    f32x4 accs[2][2] = {{acc00, acc01}, {acc10, acc11}};
    #pragma unroll
    for (int mt = 0; mt < 2; ++mt) {
        #pragma unroll
        for (int r = 0; r < 4; ++r) {
            int row = bm + mh + mt * 16 + quad * 4 + r;
            size_t rowoff = (size_t)row * ldc;
            float v0 = accs[mt][0][r] + bias0;
            float v1 = accs[mt][1][r] + bias1;
            if (EPI == 1) { v0 = __expf(2.f * v0); v1 = __expf(2.f * v1); }
            if (EPI == 3) { v0 += partial[rowoff + col0]; v1 += partial[rowoff + col1]; }
            if (EPI == 2) {
                ushort_t* C = (ushort_t*)Cv;
                C[rowoff + col0] = f2bf(v0);
                C[rowoff + col1] = f2bf(v1);
            } else {
                float* C = (float*)Cv;
                C[rowoff + col0] = v0;
                C[rowoff + col1] = v1;
            }
        }
    }
}

// ---------------------------------------------------------------------------
// K1: fused front (641 blocks)
// [0,64)    Ew = exp(2*(inp@Wq^T + bq))
// [64,320)  Eu = exp(2*(ctx@Wc^T))
// [320,576) GT[b][n,s] = sum_d WL[n,d]*ctx[b][s,d]  (bf16)
// [576,640) Y0 = inp@WR^T + bout
// [640]     zero rowsum (2048 f) for K2's atomics
// ---------------------------------------------------------------------------
__global__ __launch_bounds__(256) void fused_front(
    const float* __restrict__ inp, const float* __restrict__ ctx,
    const float* __restrict__ Wq, const float* __restrict__ bq,
    const float* __restrict__ Wc, const float* __restrict__ Wout,
    const float* __restrict__ bout,
    float* __restrict__ Ew, float* __restrict__ Eu, float* __restrict__ Y0,
    ushort_t* __restrict__ GT, float* __restrict__ rowsum)
{
    __shared__ ushort_t As[64 * 72];
    __shared__ ushort_t Ws[64 * 72];
    const int bid = blockIdx.x;

    if (bid >= 640) {
        float4 z = {0.f, 0.f, 0.f, 0.f};
        ((float4*)rowsum)[threadIdx.x * 2]     = z;
        ((float4*)rowsum)[threadIdx.x * 2 + 1] = z;
        return;
    }

    if (bid < 64) {
        gemm_body<false, false, 1>(As, Ws, inp, Wq, bq, nullptr, Ew,
                                   512, 512, 512, 512, (bid & 7) * 64, (bid >> 3) * 64);
    } else if (bid < 320) {
        int i = bid - 64;
        gemm_body<false, false, 1>(As, Ws, ctx, Wc, nullptr, nullptr, Eu,
                                   512, 512, 512, 512, (i & 31) * 64, (i >> 5) * 64);
    } else if (bid < 576) {
        int i = bid - 320;
        int b = i >> 6, j = i & 63;
        gemm_body<false, false, 2>(As, Ws, Wout, ctx + (size_t)b * 262144, nullptr,
                                   nullptr, GT + (size_t)b * 262144,
                                   512, 1024, 512, 512, (j & 7) * 64, (j >> 3) * 64);
    } else {
        int i = bid - 576;
        gemm_body<false, false, 0>(As, Ws, inp, Wout + 512, bout, nullptr, Y0,
                                   512, 512, 1024, 512, (i & 7) * 64, (i >> 3) * 64);
    }
}

// ---------------------------------------------------------------------------
// K2: E[b,t,s] = exp(V - 2*sum_d v[d]/(1 + Ew[b,t,d]*Eu[b,s,d])),  V = sum v[d]
// Wave w: 4 t's (t0 = by*16 + w*4), 8 s's. Grid (64, 8, 4) = 2048 blocks.
// k across lanes; each Eu load feeds 4 t-accumulators (load amortization+ILP).
// Also accumulates per-row sums of E via one atomicAdd per row per wave.
// No max-subtraction needed: |S| <= 3*sum|v| ~ 54, exp safe in fp32.
// ---------------------------------------------------------------------------
__global__ __launch_bounds__(256) void align_exp(
    const float* __restrict__ Ew, const float* __restrict__ Eu,
    const float* __restrict__ v, float* __restrict__ out,
    float* __restrict__ rowsum)
{
    const int lane = threadIdx.x & 63, wave = threadIdx.x >> 6;
    const int b = blockIdx.z;
    const int t0 = blockIdx.y * 16 + wave * 4;
    const int s0 = blockIdx.x * 8;

    const float* wp = Ew + (((size_t)(b * 128 + t0)) << 9);
    const float* up = Eu + (((size_t)(b * 512 + s0)) << 9);

    float acc[4][8];
    #pragma unroll
    for (int i = 0; i < 4; ++i)
        #pragma unroll
        for (int j = 0; j < 8; ++j) acc[i][j] = 0.f;
    float vsum = 0.f;

    for (int k0 = 0; k0 < 512; k0 += 64) {
        float vk = v[k0 + lane];
        vsum += vk;
        float w0 = wp[k0 + lane];
        float w1 = wp[512 + k0 + lane];
        float w2 = wp[1024 + k0 + lane];
        float w3 = wp[1536 + k0 + lane];
        #pragma unroll
        for (int j = 0; j < 8; ++j) {
            float u = up[((size_t)j << 9) + k0 + lane];
            float d0 = fmaf(w0, u, 1.f);
            float d1 = fmaf(w1, u, 1.f);
            float d2 = fmaf(w2, u, 1.f);
            float d3 = fmaf(w3, u, 1.f);
            float r0 = __builtin_amdgcn_rcpf(d0);
            float r1 = __builtin_amdgcn_rcpf(d1);
            float r2 = __builtin_amdgcn_rcpf(d2);
            float r3 = __builtin_amdgcn_rcpf(d3);
            acc[0][j] = fmaf(vk, r0, acc[0][j]);
            acc[1][j] = fmaf(vk, r1, acc[1][j]);
            acc[2][j] = fmaf(vk, r2, acc[2][j]);
            acc[3][j] = fmaf(vk, r3, acc[3][j]);
        }
    }

    float V = vsum;
    #pragma unroll
    for (int off = 32; off; off >>= 1) V += __shfl_xor(V, off, 64);

    float r0 = 0.f, r1 = 0.f, r2 = 0.f, r3 = 0.f;
    #pragma unroll
    for (int j = 0; j < 8; ++j) {
        float a0 = acc[0][j], a1 = acc[1][j], a2 = acc[2][j], a3 = acc[3][j];
        #pragma unroll
        for (int off = 32; off; off >>= 1) {
            a0 += __shfl_xor(a0, off, 64);
            a1 += __shfl_xor(a1, off, 64);
            a2 += __shfl_xor(a2, off, 64);
            a3 += __shfl_xor(a3, off, 64);
        }
        if (lane == j) {
            r0 = fmaf(-2.f, a0, V);
            r1 = fmaf(-2.f, a1, V);
            r2 = fmaf(-2.f, a2, V);
            r3 = fmaf(-2.f, a3, V);
        }
    }

    // exp + store E (lanes 0..7 hold s0+lane for rows t0..t0+3)
    float e0 = 0.f, e1 = 0.f, e2 = 0.f, e3 = 0.f;
    if (lane < 8) {
        e0 = __expf(r0); e1 = __expf(r1); e2 = __expf(r2); e3 = __expf(r3);
        size_t o = (((size_t)(b * 128 + t0)) << 9) + s0 + lane;
        out[o] = e0;
        out[o + 512] = e1;
        out[o + 1024] = e2;
        out[o + 1536] = e3;
    }
    // per-row partial sums over this wave's 8 s-columns (lanes >=8 contribute 0)
    #pragma unroll
    for (int off = 4; off; off >>= 1) {
        e0 += __shfl_xor(e0, off, 64);
        e1 += __shfl_xor(e1, off, 64);
        e2 += __shfl_xor(e2, off, 64);
        e3 += __shfl_xor(e3, off, 64);
    }
    if (lane == 0) {
        const int row = b * 128 + t0;
        atomicAdd(&rowsum[row],     e0);
        atomicAdd(&rowsum[row + 1], e1);
        atomicAdd(&rowsum[row + 2], e2);
        atomicAdd(&rowsum[row + 3], e3);
    }
}

// ---------------------------------------------------------------------------
// K3: attn = (E * rinv)_bf16 @ GT^T + Y0. Per-batch M=128, N=512, K=512.
// Grid (2,8,4). Blocks with y==0 also write alignv = E * rinv (fp32).
// ---------------------------------------------------------------------------
__global__ __launch_bounds__(256) void gemm_att_sm(
    const float* __restrict__ E, const ushort_t* __restrict__ GT,
    const float* __restrict__ Y0, const float* __restrict__ rowsum,
    float* __restrict__ attn, float* __restrict__ alignv)
{
    __shared__ ushort_t As[64 * 72];
    __shared__ ushort_t Ws[64 * 72];
    __shared__ float rinv[64];
    const int b = blockIdx.z;
    const int bm = blockIdx.x * 64;
    const int tid = threadIdx.x;

    if (tid < 64) rinv[tid] = 1.0f / rowsum[b * 128 + bm + tid];
    __syncthreads();

    gemm_body<false, true, 3, true>(As, Ws,
                                    E + (size_t)b * 65536, GT + (size_t)b * 262144,
                                    nullptr, Y0 + (size_t)b * 65536,
                                    attn + (size_t)b * 65536,
                                    512, 512, 512, 512, bm, blockIdx.y * 64, rinv);

    if (blockIdx.y == 0) {
        const float* Eb = E + (size_t)b * 65536;
        float* av = alignv + (size_t)b * 65536;
        for (int i = tid; i < 8192; i += 256) {          // 64 rows * 128 float4
            int r = i >> 7, c4 = i & 127;
            const float4* src = (const float4*)(Eb + ((size_t)(bm + r) << 9));
            float4 e = src[c4];
            float s = rinv[r];
            e.x *= s; e.y *= s; e.z *= s; e.w *= s;
            ((float4*)(av + ((size_t)(bm + r) << 9)))[c4] = e;
        }
    }
}

// ---------------------------------------------------------------------------
extern "C" void kernel_launch(void* const* d_in, const int* in_sizes, int n_in,
                              void* d_out, int out_size, void* d_ws, size_t ws_size,
                              hipStream_t stream)
{
    const float* inp  = (const float*)d_in[0];   // (4,128,512)
    const float* ctx  = (const float*)d_in[1];   // (4,512,512)
    const float* Wq   = (const float*)d_in[2];   // (512,512)
    const float* bq   = (const float*)d_in[3];   // (512)
    const float* Wc   = (const float*)d_in[4];   // (512,512)
    const float* v    = (const float*)d_in[5];   // (512)
    const float* Wout = (const float*)d_in[6];   // (512,1024)
    const float* bout = (const float*)d_in[7];   // (512)

    float* out    = (float*)d_out;
    float* attn   = out;              // 262144 floats
    float* alignv = out + 262144;     // 262144 floats

    float* ws = (float*)d_ws;
    float* Ew   = ws;                            // 262144 f
    float* Eu   = ws + 262144;                   // 1048576 f
    float* Y0   = ws + 1310720;                  // 262144 f
    float* E    = ws + 1572864;                  // 262144 f (exp of raw scores)
    ushort_t* GT = (ushort_t*)(ws + 1835008);    // 1048576 u16 (= 524288 f)
    float* rowsum = ws + 2359296;                // 2048 f

    fused_front<<<dim3(641), 256, 0, stream>>>(inp, ctx, Wq, bq, Wc, Wout, bout,
                                               Ew, Eu, Y0, GT, rowsum);
    align_exp<<<dim3(64, 8, 4), 256, 0, stream>>>(Ew, Eu, v, E, rowsum);
    gemm_att_sm<<<dim3(2, 8, 4), 256, 0, stream>>>(E, GT, Y0, rowsum, attn, alignv);
}

// Round 2
// 119.945 us; speedup vs baseline: 1.4427x; 1.4427x over previous
//
#include <hip/hip_runtime.h>
#include <hip/hip_bf16.h>
#include <math.h>

// B=4, T=128, S=512, D=512. Outputs: attn_h (4,128,512) then align (4,128,512), fp32.
// 4-kernel pipeline (R7 = R5 + paired-rcp K2):
//   K1 fused_front (640): Ew=exp(2(inp@Wq^T+bq)), Eu=exp(2 ctx@Wc^T),
//      GT[b]=(WL@ctx_b^T) bf16, Y0=inp@WR^T+bout
//   K2 align (2048): Sraw[b,t,s] = V - 2*sum_d v[d]/(1+Ew*Eu)  (== sum v*tanh)
//      paired denominators: v_a/A + v_b/B = (v_a*B+v_b*A)/(A*B) -> 1 rcp / 2 elems
//   K3 softmax (512): alignv (fp32, d_out) + P_bf (bf16, ws), exp once/element
//   K4 gemm_att (64): attn = P_bf @ GT^T + Y0   (MFMA, K=512)

typedef __attribute__((ext_vector_type(8))) short short8;
typedef __attribute__((ext_vector_type(4))) float f32x4;
typedef unsigned short ushort_t;

static __device__ __forceinline__ unsigned short f2bf(float x) {
    union { __hip_bfloat16 h; unsigned short u; } c;
    c.h = __float2bfloat16(x);
    return c.u;
}
static __device__ __forceinline__ int bf2x(float lo, float hi) {
    return (int)(((unsigned)f2bf(hi) << 16) | (unsigned)f2bf(lo));
}

template<bool BF>
static __device__ __forceinline__ void load16(const void* base, size_t elemoff,
                                              int4& r0, int4& r1) {
    if (BF) {
        const int4* p = (const int4*)((const ushort_t*)base + elemoff);
        r0 = p[0]; r1 = p[1];
    } else {
        const float4* p = (const float4*)((const float*)base + elemoff);
        float4 a = p[0], b = p[1], c = p[2], d = p[3];
        r0.x = bf2x(a.x, a.y); r0.y = bf2x(a.z, a.w);
        r0.z = bf2x(b.x, b.y); r0.w = bf2x(b.z, b.w);
        r1.x = bf2x(c.x, c.y); r1.y = bf2x(c.z, c.w);
        r1.z = bf2x(d.x, d.y); r1.w = bf2x(d.z, d.w);
    }
}

// ---------------------------------------------------------------------------
// MFMA NT GEMM tile: C[m,n] = sum_k A[m,k]*W[n,k] (+bias). 64x64 tile, BK=64,
// 256 thr = 4 waves (2x2 of 32x32), 2x2 MFMA 16x16x32 per 32-K step.
// LDS rows padded to 72 bf16 (<=2-way bank aliasing on b128 = free).
// EPI: 0 fp32+bias; 1 fp32 exp(2*(x+bias)); 2 bf16; 3 fp32 + partial[].
// ---------------------------------------------------------------------------
template<bool A_BF, bool W_BF, int EPI>
static __device__ __forceinline__ void gemm_body(
    ushort_t* As, ushort_t* Ws,
    const void* A, const void* W, const float* bias, const float* partial,
    void* Cv, int K, int lda, int ldw, int ldc, int bm, int bn)
{
    const int tid = threadIdx.x;
    const int wave = tid >> 6, lane = tid & 63;
    const int mh = (wave & 1) * 32, nh = (wave >> 1) * 32;
    const int quad = lane >> 4, l16 = lane & 15;
    const int srow = tid >> 2, schunk = tid & 3;

    const size_t aoff = (size_t)(bm + srow) * lda + schunk * 16;
    const size_t woff = (size_t)(bn + srow) * ldw + schunk * 16;
    int4* AsW = (int4*)&As[srow * 72 + schunk * 16];
    int4* WsW = (int4*)&Ws[srow * 72 + schunk * 16];

    f32x4 acc00 = {0.f, 0.f, 0.f, 0.f}, acc01 = acc00, acc10 = acc00, acc11 = acc00;

    int4 a0r, a1r, w0r, w1r;
    load16<A_BF>(A, aoff, a0r, a1r);
    load16<W_BF>(W, woff, w0r, w1r);

    for (int k0 = 0; k0 < K; k0 += 64) {
        AsW[0] = a0r; AsW[1] = a1r;
        WsW[0] = w0r; WsW[1] = w1r;
        __syncthreads();
        if (k0 + 64 < K) {
            load16<A_BF>(A, aoff + k0 + 64, a0r, a1r);
            load16<W_BF>(W, woff + k0 + 64, w0r, w1r);
        }
        #pragma unroll
        for (int kk = 0; kk < 64; kk += 32) {
            short8 a0 = *(const short8*)&As[(mh + l16) * 72 + kk + quad * 8];
            short8 a1 = *(const short8*)&As[(mh + 16 + l16) * 72 + kk + quad * 8];
            short8 b0 = *(const short8*)&Ws[(nh + l16) * 72 + kk + quad * 8];
            short8 b1 = *(const short8*)&Ws[(nh + 16 + l16) * 72 + kk + quad * 8];
            acc00 = __builtin_amdgcn_mfma_f32_16x16x32_bf16(a0, b0, acc00, 0, 0, 0);
            acc01 = __builtin_amdgcn_mfma_f32_16x16x32_bf16(a0, b1, acc01, 0, 0, 0);
            acc10 = __builtin_amdgcn_mfma_f32_16x16x32_bf16(a1, b0, acc10, 0, 0, 0);
            acc11 = __builtin_amdgcn_mfma_f32_16x16x32_bf16(a1, b1, acc11, 0, 0, 0);
        }
        __syncthreads();
    }

    const int col0 = bn + nh + l16;
    const int col1 = col0 + 16;
    float bias0 = bias ? bias[col0] : 0.f;
    float bias1 = bias ? bias[col1] : 0.f;

    f32x4 accs[2][2] = {{acc00, acc01}, {acc10, acc11}};
    #pragma unroll
    for (int mt = 0; mt < 2; ++mt) {
        #pragma unroll
        for (int r = 0; r < 4; ++r) {
            int row = bm + mh + mt * 16 + quad * 4 + r;
            size_t rowoff = (size_t)row * ldc;
            float v0 = accs[mt][0][r] + bias0;
            float v1 = accs[mt][1][r] + bias1;
            if (EPI == 1) { v0 = __expf(2.f * v0); v1 = __expf(2.f * v1); }
            if (EPI == 3) { v0 += partial[rowoff + col0]; v1 += partial[rowoff + col1]; }
            if (EPI == 2) {
                ushort_t* C = (ushort_t*)Cv;
                C[rowoff + col0] = f2bf(v0);
                C[rowoff + col1] = f2bf(v1);
            } else {
                float* C = (float*)Cv;
                C[rowoff + col0] = v0;
                C[rowoff + col1] = v1;
            }
        }
    }
}

// ---------------------------------------------------------------------------
// K1: fused front (640 GEMM blocks)
// [0,64)    Ew = exp(2*(inp@Wq^T + bq))
// [64,320)  Eu = exp(2*(ctx@Wc^T))
// [320,576) GT[b][n,s] = sum_d WL[n,d]*ctx[b][s,d]  (bf16)
// [576,640) Y0 = inp@WR^T + bout
// ---------------------------------------------------------------------------
__global__ __launch_bounds__(256) void fused_front(
    const float* __restrict__ inp, const float* __restrict__ ctx,
    const float* __restrict__ Wq, const float* __restrict__ bq,
    const float* __restrict__ Wc, const float* __restrict__ Wout,
    const float* __restrict__ bout,
    float* __restrict__ Ew, float* __restrict__ Eu, float* __restrict__ Y0,
    ushort_t* __restrict__ GT)
{
    __shared__ ushort_t As[64 * 72];
    __shared__ ushort_t Ws[64 * 72];
    const int bid = blockIdx.x;

    if (bid < 64) {
        gemm_body<false, false, 1>(As, Ws, inp, Wq, bq, nullptr, Ew,
                                   512, 512, 512, 512, (bid & 7) * 64, (bid >> 3) * 64);
    } else if (bid < 320) {
        int i = bid - 64;
        gemm_body<false, false, 1>(As, Ws, ctx, Wc, nullptr, nullptr, Eu,
                                   512, 512, 512, 512, (i & 31) * 64, (i >> 5) * 64);
    } else if (bid < 576) {
        int i = bid - 320;
        int b = i >> 6, j = i & 63;
        gemm_body<false, false, 2>(As, Ws, Wout, ctx + (size_t)b * 262144, nullptr,
                                   nullptr, GT + (size_t)b * 262144,
                                   512, 1024, 512, 512, (j & 7) * 64, (j >> 3) * 64);
    } else {
        int i = bid - 576;
        gemm_body<false, false, 0>(As, Ws, inp, Wout + 512, bout, nullptr, Y0,
                                   512, 512, 1024, 512, (i & 7) * 64, (i >> 3) * 64);
    }
}

// ---------------------------------------------------------------------------
// K2: Sraw[b,t,s] = V - 2*sum_d v[d]/(1 + Ew[b,t,d]*Eu[b,s,d]),  V = sum v[d]
// Wave w: 4 t's (t0 = by*16 + w*4), 8 s's. Grid (64, 8, 4) = 2048 blocks
// (exactly fills the GPU: 8 blocks/CU, 2048 thr/CU).
// k across lanes. Paired denominators: two d-elements (k0+lane, k0+64+lane)
// share one rcp:  v_a/A + v_b/B = (v_a*B + v_b*A) * rcp(A*B).
// Main loop: 768 fma-class + 128 rcp per wave (was 1024 + 256).
// ---------------------------------------------------------------------------
__global__ __launch_bounds__(256) void align_kernel(
    const float* __restrict__ Ew, const float* __restrict__ Eu,
    const float* __restrict__ v, float* __restrict__ out)
{
    const int lane = threadIdx.x & 63, wave = threadIdx.x >> 6;
    const int b = blockIdx.z;
    const int t0 = blockIdx.y * 16 + wave * 4;
    const int s0 = blockIdx.x * 8;

    const float* wp = Ew + (((size_t)(b * 128 + t0)) << 9);
    const float* up = Eu + (((size_t)(b * 512 + s0)) << 9);

    float acc[4][8];
    #pragma unroll
    for (int i = 0; i < 4; ++i)
        #pragma unroll
        for (int j = 0; j < 8; ++j) acc[i][j] = 0.f;
    float vsum = 0.f;

    for (int k0 = 0; k0 < 512; k0 += 128) {
        float va = v[k0 + lane];
        float vb = v[k0 + 64 + lane];
        vsum += va + vb;
        float wa[4], wb[4];
        #pragma unroll
        for (int i = 0; i < 4; ++i) {
            wa[i] = wp[i * 512 + k0 + lane];
            wb[i] = wp[i * 512 + k0 + 64 + lane];
        }
        #pragma unroll
        for (int j = 0; j < 8; ++j) {
            const float* u = up + ((size_t)j << 9) + k0 + lane;
            float ua = u[0];
            float ub = u[64];
            #pragma unroll
            for (int i = 0; i < 4; ++i) {
                float A = fmaf(wa[i], ua, 1.f);     // 1 + Ew_a*Eu_a  (>= 1)
                float B = fmaf(wb[i], ub, 1.f);     // 1 + Ew_b*Eu_b  (>= 1)
                float num = fmaf(va, B, vb * A);    // v_a*B + v_b*A
                float r = __builtin_amdgcn_rcpf(A * B);  // den <= (1+e^16)^2, safe
                acc[i][j] = fmaf(num, r, acc[i][j]);
            }
        }
    }

    float V = vsum;
    #pragma unroll
    for (int off = 32; off; off >>= 1) V += __shfl_xor(V, off, 64);

    float r0 = 0.f, r1 = 0.f, r2 = 0.f, r3 = 0.f;
    #pragma unroll
    for (int j = 0; j < 8; ++j) {
        float a0 = acc[0][j], a1 = acc[1][j], a2 = acc[2][j], a3 = acc[3][j];
        #pragma unroll
        for (int off = 32; off; off >>= 1) {
            a0 += __shfl_xor(a0, off, 64);
            a1 += __shfl_xor(a1, off, 64);
            a2 += __shfl_xor(a2, off, 64);
            a3 += __shfl_xor(a3, off, 64);
        }
        if (lane == j) {
            r0 = fmaf(-2.f, a0, V);
            r1 = fmaf(-2.f, a1, V);
            r2 = fmaf(-2.f, a2, V);
            r3 = fmaf(-2.f, a3, V);
        }
    }
    if (lane < 8) {
        size_t o = (((size_t)(b * 128 + t0)) << 9) + s0 + lane;
        out[o] = r0;
        out[o + 512] = r1;
        out[o + 1024] = r2;
        out[o + 1536] = r3;
    }
}

// ---------------------------------------------------------------------------
// K3: softmax over rows of 512. Reads Sraw, writes fp32 alignv + bf16 P.
// ---------------------------------------------------------------------------
__global__ __launch_bounds__(256) void softmax_512(
    const float* __restrict__ Sraw, float* __restrict__ alignv,
    ushort_t* __restrict__ pbf)
{
    const int row = blockIdx.x;
    const float* p = Sraw + ((size_t)row << 9);
    float* a = alignv + ((size_t)row << 9);
    ushort_t* q = pbf + ((size_t)row << 9);
    const int tid = threadIdx.x;
    float x0 = p[tid];
    float x1 = p[tid + 256];

    float m = fmaxf(x0, x1);
    #pragma unroll
    for (int off = 32; off > 0; off >>= 1)
        m = fmaxf(m, __shfl_xor(m, off, 64));
    __shared__ float redm[4];
    __shared__ float reds[4];
    const int wave = tid >> 6;
    if ((tid & 63) == 0) redm[wave] = m;
    __syncthreads();
    m = fmaxf(fmaxf(redm[0], redm[1]), fmaxf(redm[2], redm[3]));

    float e0 = __expf(x0 - m);
    float e1 = __expf(x1 - m);
    float s = e0 + e1;
    #pragma unroll
    for (int off = 32; off > 0; off >>= 1)
        s += __shfl_xor(s, off, 64);
    if ((tid & 63) == 0) reds[wave] = s;
    __syncthreads();
    s = reds[0] + reds[1] + reds[2] + reds[3];
    float r = 1.0f / s;
    float p0 = e0 * r, p1 = e1 * r;
    a[tid] = p0;
    a[tid + 256] = p1;
    q[tid] = f2bf(p0);
    q[tid + 256] = f2bf(p1);
}

// ---------------------------------------------------------------------------
// K4: attn = P_bf @ GT^T + Y0. Per-batch M=128, N=512, K=512. Grid (2,8,4).
// ---------------------------------------------------------------------------
__global__ __launch_bounds__(256) void gemm_att(
    const ushort_t* __restrict__ P, const ushort_t* __restrict__ GT,
    const float* __restrict__ Y0, float* __restrict__ attn)
{
    __shared__ ushort_t As[64 * 72];
    __shared__ ushort_t Ws[64 * 72];
    const int b = blockIdx.z;
    gemm_body<true, true, 3>(As, Ws,
                             P + (size_t)b * 65536, GT + (size_t)b * 262144,
                             nullptr, Y0 + (size_t)b * 65536,
                             attn + (size_t)b * 65536,
                             512, 512, 512, 512, blockIdx.x * 64, blockIdx.y * 64);
}

// ---------------------------------------------------------------------------
extern "C" void kernel_launch(void* const* d_in, const int* in_sizes, int n_in,
                              void* d_out, int out_size, void* d_ws, size_t ws_size,
                              hipStream_t stream)
{
    const float* inp  = (const float*)d_in[0];   // (4,128,512)
    const float* ctx  = (const float*)d_in[1];   // (4,512,512)
    const float* Wq   = (const float*)d_in[2];   // (512,512)
    const float* bq   = (const float*)d_in[3];   // (512)
    const float* Wc   = (const float*)d_in[4];   // (512,512)
    const float* v    = (const float*)d_in[5];   // (512)
    const float* Wout = (const float*)d_in[6];   // (512,1024)
    const float* bout = (const float*)d_in[7];   // (512)

    float* out    = (float*)d_out;
    float* attn   = out;              // 262144 floats
    float* alignv = out + 262144;     // 262144 floats

    float* ws = (float*)d_ws;
    float* Ew   = ws;                          // 262144 f
    float* Eu   = ws + 262144;                 // 1048576 f
    float* Y0   = ws + 1310720;                // 262144 f
    float* Sraw = ws + 1572864;                // 262144 f
    ushort_t* GT   = (ushort_t*)(ws + 1835008); // 1048576 u16 (= 524288 f)
    ushort_t* P_bf = (ushort_t*)(ws + 2359296); // 262144 u16

    fused_front<<<dim3(640), 256, 0, stream>>>(inp, ctx, Wq, bq, Wc, Wout, bout,
                                               Ew, Eu, Y0, GT);
    align_kernel<<<dim3(64, 8, 4), 256, 0, stream>>>(Ew, Eu, v, Sraw);
    softmax_512<<<dim3(512), 256, 0, stream>>>(Sraw, alignv, P_bf);
    gemm_att<<<dim3(2, 8, 4), 256, 0, stream>>>(P_bf, GT, Y0, attn);
}